// Round 1
// baseline (425.236 us; speedup 1.0000x reference)
//
#include <hip/hip_runtime.h>
#include <cstdint>
#include <cstddef>

// Problem constants
#define NB   2
#define LQ   2048
#define LKK  2048
#define LS   256
#define HID  1024
#define NH   16
#define LSK  2304   // LS + LK

#define DEV __device__ __forceinline__

typedef __bf16 bf16x8 __attribute__((ext_vector_type(8)));
typedef float  f32x4  __attribute__((ext_vector_type(4)));
typedef unsigned short us8 __attribute__((ext_vector_type(8)));

DEV unsigned short f2bf(float f) {
  unsigned int u = __builtin_bit_cast(unsigned int, f);
  u = (u + 0x7fffu + ((u >> 16) & 1u)) >> 16;  // RNE
  return (unsigned short)u;
}
DEV float bf2f(unsigned short h) {
  unsigned int u = ((unsigned int)h) << 16;
  return __builtin_bit_cast(float, u);
}
DEV bf16x8 ld_frag(const void* p) {
  uint4 v = *(const uint4*)p;
  return __builtin_bit_cast(bf16x8, v);
}
DEV void gload_lds16(const unsigned short* g, unsigned short* l) {
  __builtin_amdgcn_global_load_lds((const __attribute__((address_space(1))) unsigned int*)g,
                                   (__attribute__((address_space(3))) unsigned int*)l,
                                   16, 0, 0);
}

// ---------------- fp32 -> bf16 cast ----------------
__global__ void cast_kernel(const float* __restrict__ in, unsigned short* __restrict__ out, int n8) {
  for (int i = blockIdx.x * blockDim.x + threadIdx.x; i < n8; i += gridDim.x * blockDim.x) {
    const float4* p = (const float4*)(in + (size_t)i * 8);
    float4 a = p[0], b = p[1];
    us8 o;
    o[0] = f2bf(a.x); o[1] = f2bf(a.y); o[2] = f2bf(a.z); o[3] = f2bf(a.w);
    o[4] = f2bf(b.x); o[5] = f2bf(b.y); o[6] = f2bf(b.z); o[7] = f2bf(b.w);
    *(us8*)(out + (size_t)i * 8) = o;
  }
}

// ---------------- sampled^T into KcT/VcT cols [0,256) ----------------
// KcT/VcT layout: [b][n=HID][s=LSK] bf16. grid (LS/64, HID/64, B), block 256.
__global__ __launch_bounds__(256)
void samp_T(const float* __restrict__ samp, unsigned short* __restrict__ KcT,
            unsigned short* __restrict__ VcT) {
  __shared__ unsigned short tl[64][65];
  const int b = blockIdx.z, st = blockIdx.x, nt = blockIdx.y;
  const int tid = threadIdx.x;
  const int nl = tid & 63, sq = tid >> 6;
#pragma unroll
  for (int j = 0; j < 16; ++j) {
    int sl = sq * 16 + j;
    tl[sl][nl] = f2bf(samp[(size_t)(b * LS + st * 64 + sl) * HID + nt * 64 + nl]);
  }
  __syncthreads();
#pragma unroll
  for (int wv = 0; wv < 2; ++wv) {
    int idx = wv * 256 + tid;
    int n_local = idx >> 3, sc = idx & 7;
    us8 v;
#pragma unroll
    for (int j = 0; j < 8; ++j) v[j] = tl[sc * 8 + j][n_local];
    size_t o = (size_t)(b * HID + nt * 64 + n_local) * LSK + st * 64 + sc * 8;
    *(us8*)(KcT + o) = v;
    *(us8*)(VcT + o) = v;
  }
}

// ---------------- generic bf16 GEMM: C = A[M,K] * BT[N,K]^T (+bias)*oscale ----------------
// 128x128 tile, BK=64, 4 waves (2x2), global_load_lds staging with XOR chunk swizzle.
// EPI: 0 = bf16 standard out[m*ldo+n]; 1 = bf16 transposed out[n*ldo+moff+m]; 2 = f32 standard.
// BIAS_ROW: 0 = bias[n], 1 = bias[m].
template<int BIAS_ROW, int EPI>
__global__ __launch_bounds__(256, 2)
void gemm_bt(const unsigned short* __restrict__ A, const unsigned short* __restrict__ BT,
             const float* __restrict__ bias, void* __restrict__ out,
             int M, int N, int K, int ldo, int moff,
             size_t a_zs, size_t bt_zs, size_t o_zs, float oscale) {
  __shared__ unsigned short lA[128 * 64];
  __shared__ unsigned short lB[128 * 64];
  const int tid = threadIdx.x, l = tid & 63, w = tid >> 6;
  const int wr = w >> 1, wc = w & 1;
  const int m0 = blockIdx.y * 128, n0 = blockIdx.x * 128;
  const int z = blockIdx.z;
  A += (size_t)z * a_zs;
  BT += (size_t)z * bt_zs;
  f32x4 acc[4][4] = {};
  const int nk = K >> 6;
  for (int kt = 0; kt < nk; ++kt) {
    const int k0 = kt << 6;
#pragma unroll
    for (int it = 0; it < 4; ++it) {
      int s = it * 256 + tid;
      int t = s >> 3, c = s & 7, g = c ^ (t & 7);
      gload_lds16(A + (size_t)(m0 + t) * K + (k0 + g * 8), lA + (size_t)s * 8);
      gload_lds16(BT + (size_t)(n0 + t) * K + (k0 + g * 8), lB + (size_t)s * 8);
    }
    __syncthreads();
#pragma unroll
    for (int ks = 0; ks < 2; ++ks) {
      bf16x8 af[4], bfr[4];
#pragma unroll
      for (int mi = 0; mi < 4; ++mi) {
        int row = wr * 64 + mi * 16 + (l & 15);
        int ch = (ks * 4 + (l >> 4)) ^ (row & 7);
        af[mi] = ld_frag((const char*)lA + row * 128 + ch * 16);
      }
#pragma unroll
      for (int ni = 0; ni < 4; ++ni) {
        int row = wc * 64 + ni * 16 + (l & 15);
        int ch = (ks * 4 + (l >> 4)) ^ (row & 7);
        bfr[ni] = ld_frag((const char*)lB + row * 128 + ch * 16);
      }
#pragma unroll
      for (int mi = 0; mi < 4; ++mi)
#pragma unroll
        for (int ni = 0; ni < 4; ++ni)
          acc[mi][ni] = __builtin_amdgcn_mfma_f32_16x16x32_bf16(af[mi], bfr[ni], acc[mi][ni], 0, 0, 0);
    }
    __syncthreads();
  }
  const int r4 = (l >> 4) * 4;
#pragma unroll
  for (int mi = 0; mi < 4; ++mi) {
    const int mbase = m0 + wr * 64 + mi * 16 + r4;
#pragma unroll
    for (int ni = 0; ni < 4; ++ni) {
      const int n = n0 + wc * 64 + ni * 16 + (l & 15);
      f32x4 v = acc[mi][ni];
      if (BIAS_ROW) {
#pragma unroll
        for (int r = 0; r < 4; ++r) v[r] = (v[r] + bias[mbase + r]) * oscale;
      } else {
        const float bn = bias[n];
#pragma unroll
        for (int r = 0; r < 4; ++r) v[r] = (v[r] + bn) * oscale;
      }
      if (EPI == 0) {
        unsigned short* o = (unsigned short*)out + (size_t)z * o_zs;
#pragma unroll
        for (int r = 0; r < 4; ++r) o[(size_t)(mbase + r) * ldo + n] = f2bf(v[r]);
      } else if (EPI == 1) {
        unsigned short* o = (unsigned short*)out + (size_t)z * o_zs;
        ushort4 p;
        p.x = f2bf(v[0]); p.y = f2bf(v[1]); p.z = f2bf(v[2]); p.w = f2bf(v[3]);
        *(ushort4*)(o + (size_t)n * ldo + moff + mbase) = p;
      } else {
        float* o = (float*)out + (size_t)z * o_zs;
#pragma unroll
        for (int r = 0; r < 4; ++r) o[(size_t)(mbase + r) * ldo + n] = v[r];
      }
    }
  }
}

// ---------------- attention pass A: per-row online max + logsumexp ----------------
// Qb pre-scaled by 1/8. grid (LQ/128, B*NH), block 256. alpha[bh*LQ + q] = m + ln(sum).
__global__ __launch_bounds__(256, 2)
void attn_stats(const unsigned short* __restrict__ Qb, const unsigned short* __restrict__ Kn,
                float* __restrict__ alpha) {
  __shared__ unsigned short lQ[128 * 64];
  __shared__ unsigned short lK[64 * 64];
  const int tid = threadIdx.x, l = tid & 63, w = tid >> 6;
  const int qt = blockIdx.x, bh = blockIdx.y, b = bh >> 4, h = bh & 15;
  const unsigned short* Qg = Qb + (size_t)(b * LQ + qt * 128) * HID + h * 64;
  const unsigned short* Kg = Kn + (size_t)(b * LKK) * HID + h * 64;
#pragma unroll
  for (int it = 0; it < 4; ++it) {
    int s = it * 256 + tid, t = s >> 3, c = s & 7, g = c ^ (t & 7);
    gload_lds16(Qg + (size_t)t * HID + g * 8, lQ + (size_t)s * 8);
  }
  __syncthreads();
  bf16x8 qf[2][2];
#pragma unroll
  for (int qi = 0; qi < 2; ++qi)
#pragma unroll
    for (int ds = 0; ds < 2; ++ds) {
      int row = w * 32 + qi * 16 + (l & 15);
      int ch = (ds * 4 + (l >> 4)) ^ (row & 7);
      qf[qi][ds] = ld_frag((const char*)lQ + row * 128 + ch * 16);
    }
  float mx[2][4], sm[2][4];
#pragma unroll
  for (int qi = 0; qi < 2; ++qi)
#pragma unroll
    for (int r = 0; r < 4; ++r) { mx[qi][r] = -1e30f; sm[qi][r] = 0.0f; }
  for (int kt = 0; kt < 32; ++kt) {
#pragma unroll
    for (int it = 0; it < 2; ++it) {
      int s = it * 256 + tid, t = s >> 3, c = s & 7, g = c ^ (t & 7);
      gload_lds16(Kg + (size_t)(kt * 64 + t) * HID + g * 8, lK + (size_t)s * 8);
    }
    __syncthreads();
    f32x4 e[2][4] = {};
#pragma unroll
    for (int ds = 0; ds < 2; ++ds) {
      bf16x8 kf[4];
#pragma unroll
      for (int ki = 0; ki < 4; ++ki) {
        int row = ki * 16 + (l & 15);
        int ch = (ds * 4 + (l >> 4)) ^ (row & 7);
        kf[ki] = ld_frag((const char*)lK + row * 128 + ch * 16);
      }
#pragma unroll
      for (int qi = 0; qi < 2; ++qi)
#pragma unroll
        for (int ki = 0; ki < 4; ++ki)
          e[qi][ki] = __builtin_amdgcn_mfma_f32_16x16x32_bf16(qf[qi][ds], kf[ki], e[qi][ki], 0, 0, 0);
    }
#pragma unroll
    for (int qi = 0; qi < 2; ++qi)
#pragma unroll
      for (int r = 0; r < 4; ++r) {
        float v0 = e[qi][0][r], v1 = e[qi][1][r], v2 = e[qi][2][r], v3 = e[qi][3][r];
        float tm = fmaxf(fmaxf(v0, v1), fmaxf(v2, v3));
        float mo = mx[qi][r], mn = fmaxf(mo, tm);
        sm[qi][r] = sm[qi][r] * __expf(mo - mn)
                  + __expf(v0 - mn) + __expf(v1 - mn) + __expf(v2 - mn) + __expf(v3 - mn);
        mx[qi][r] = mn;
      }
    __syncthreads();
  }
#pragma unroll
  for (int qi = 0; qi < 2; ++qi)
#pragma unroll
    for (int r = 0; r < 4; ++r) {
      float mm = mx[qi][r], ss = sm[qi][r];
#pragma unroll
      for (int mask = 1; mask < 16; mask <<= 1) {
        float om = __shfl_xor(mm, mask, 64);
        float os = __shfl_xor(ss, mask, 64);
        float mn = fmaxf(mm, om);
        ss = ss * __expf(mm - mn) + os * __expf(om - mn);
        mm = mn;
      }
      if ((l & 15) == 0)
        alpha[(size_t)bh * LQ + qt * 128 + w * 32 + qi * 16 + (l >> 4) * 4 + r] = mm + __logf(ss);
    }
}

// ---------------- attention pass B: attn write + PV ----------------
__global__ __launch_bounds__(256, 2)
void attn_pv(const unsigned short* __restrict__ Qb, const unsigned short* __restrict__ Kn,
             const unsigned short* __restrict__ Vt, const float* __restrict__ alpha,
             float* __restrict__ attn_out, unsigned short* __restrict__ xpre) {
  __shared__ unsigned short lQ[128 * 64];
  __shared__ unsigned short lK[64 * 64];
  __shared__ unsigned short lV[64 * 64];
  __shared__ unsigned short lP[4 * 2048];
  const int tid = threadIdx.x, l = tid & 63, w = tid >> 6;
  const int qt = blockIdx.x, bh = blockIdx.y, b = bh >> 4, h = bh & 15;
  const unsigned short* Qg = Qb + (size_t)(b * LQ + qt * 128) * HID + h * 64;
  const unsigned short* Kg = Kn + (size_t)(b * LKK) * HID + h * 64;
  const unsigned short* Vg = Vt + ((size_t)b * HID + h * 64) * LKK;  // [d][t] rows
  unsigned short* lPw = lP + w * 2048;
#pragma unroll
  for (int it = 0; it < 4; ++it) {
    int s = it * 256 + tid, t = s >> 3, c = s & 7, g = c ^ (t & 7);
    gload_lds16(Qg + (size_t)t * HID + g * 8, lQ + (size_t)s * 8);
  }
  float al[2][4];
#pragma unroll
  for (int qi = 0; qi < 2; ++qi)
#pragma unroll
    for (int r = 0; r < 4; ++r)
      al[qi][r] = alpha[(size_t)bh * LQ + qt * 128 + w * 32 + qi * 16 + (l >> 4) * 4 + r];
  __syncthreads();
  bf16x8 qf[2][2];
#pragma unroll
  for (int qi = 0; qi < 2; ++qi)
#pragma unroll
    for (int ds = 0; ds < 2; ++ds) {
      int row = w * 32 + qi * 16 + (l & 15);
      int ch = (ds * 4 + (l >> 4)) ^ (row & 7);
      qf[qi][ds] = ld_frag((const char*)lQ + row * 128 + ch * 16);
    }
  f32x4 x[2][4] = {};
  float* attn_base = attn_out + ((size_t)bh * LQ + qt * 128) * LKK;
  for (int kt = 0; kt < 32; ++kt) {
#pragma unroll
    for (int it = 0; it < 2; ++it) {
      int s = it * 256 + tid, t = s >> 3, c = s & 7, g = c ^ (t & 7);
      gload_lds16(Kg + (size_t)(kt * 64 + t) * HID + g * 8, lK + (size_t)s * 8);
      gload_lds16(Vg + (size_t)t * LKK + kt * 64 + g * 8, lV + (size_t)s * 8);
    }
    __syncthreads();
    f32x4 e[2][4] = {};
#pragma unroll
    for (int ds = 0; ds < 2; ++ds) {
      bf16x8 kf[4];
#pragma unroll
      for (int ki = 0; ki < 4; ++ki) {
        int row = ki * 16 + (l & 15);
        int ch = (ds * 4 + (l >> 4)) ^ (row & 7);
        kf[ki] = ld_frag((const char*)lK + row * 128 + ch * 16);
      }
#pragma unroll
      for (int qi = 0; qi < 2; ++qi)
#pragma unroll
        for (int ki = 0; ki < 4; ++ki)
          e[qi][ki] = __builtin_amdgcn_mfma_f32_16x16x32_bf16(qf[qi][ds], kf[ki], e[qi][ki], 0, 0, 0);
    }
    // softmax-exp, stash bf16 P tile in per-wave LDS (XOR-swizzled 16B chunks)
#pragma unroll
    for (int qi = 0; qi < 2; ++qi)
#pragma unroll
      for (int ki = 0; ki < 4; ++ki)
#pragma unroll
        for (int r = 0; r < 4; ++r) {
          float p = __expf(e[qi][ki][r] - al[qi][r]);
          int rowq = qi * 16 + (l >> 4) * 4 + r;
          int k = ki * 16 + (l & 15);
          lPw[rowq * 64 + (((k >> 3) ^ (rowq & 7)) * 8) + (k & 7)] = f2bf(p);
        }
    __syncthreads();  // order LDS writes vs typed reads (TBAA-safe), cheap
    // coalesced fp32 attention store (float4 x2 per lane per chunk)
    {
      float* ab = attn_base + (size_t)(w * 32) * LKK + kt * 64;
#pragma unroll
      for (int i2 = 0; i2 < 4; ++i2) {
        int s = i2 * 64 + l;
        int rowq = s >> 3, cs = s & 7, g = cs ^ (rowq & 7);
        us8 hv = *(const us8*)(lPw + (size_t)s * 8);
        float4 f0, f1;
        f0.x = bf2f(hv[0]); f0.y = bf2f(hv[1]); f0.z = bf2f(hv[2]); f0.w = bf2f(hv[3]);
        f1.x = bf2f(hv[4]); f1.y = bf2f(hv[5]); f1.z = bf2f(hv[6]); f1.w = bf2f(hv[7]);
        float* dst = ab + (size_t)rowq * LKK + g * 8;
        *(float4*)dst = f0;
        *((float4*)dst + 1) = f1;
      }
    }
    // PV: x += P * V
#pragma unroll
    for (int ks = 0; ks < 2; ++ks) {
      bf16x8 pa[2], vb[4];
#pragma unroll
      for (int qi = 0; qi < 2; ++qi) {
        int row = qi * 16 + (l & 15);
        int ch = (ks * 4 + (l >> 4)) ^ (row & 7);
        pa[qi] = ld_frag((const char*)lPw + row * 128 + ch * 16);
      }
#pragma unroll
      for (int df = 0; df < 4; ++df) {
        int row = df * 16 + (l & 15);
        int ch = (ks * 4 + (l >> 4)) ^ (row & 7);
        vb[df] = ld_frag((const char*)lV + row * 128 + ch * 16);
      }
#pragma unroll
      for (int qi = 0; qi < 2; ++qi)
#pragma unroll
        for (int df = 0; df < 4; ++df)
          x[qi][df] = __builtin_amdgcn_mfma_f32_16x16x32_bf16(pa[qi], vb[df], x[qi][df], 0, 0, 0);
    }
    __syncthreads();
  }
#pragma unroll
  for (int qi = 0; qi < 2; ++qi)
#pragma unroll
    for (int df = 0; df < 4; ++df)
#pragma unroll
      for (int r = 0; r < 4; ++r)
        xpre[(size_t)(b * LQ + qt * 128 + w * 32 + qi * 16 + (l >> 4) * 4 + r) * HID
             + h * 64 + df * 16 + (l & 15)] = f2bf(x[qi][df][r]);
}

// ---------------- launcher ----------------
extern "C" void kernel_launch(void* const* d_in, const int* in_sizes, int n_in,
                              void* d_out, int out_size, void* d_ws, size_t ws_size,
                              hipStream_t stream) {
  (void)in_sizes; (void)n_in; (void)out_size; (void)ws_size;
  const float* query   = (const float*)d_in[0];
  const float* sampled = (const float*)d_in[1];
  const float* key     = (const float*)d_in[2];
  const float* value   = (const float*)d_in[3];
  const float* Wq = (const float*)d_in[4];  const float* bq = (const float*)d_in[5];
  const float* Wk = (const float*)d_in[6];  const float* bk = (const float*)d_in[7];
  const float* Wv = (const float*)d_in[8];  const float* bv = (const float*)d_in[9];
  const float* Wo = (const float*)d_in[10]; const float* bo = (const float*)d_in[11];
  const float* rW = (const float*)d_in[12]; const float* rb = (const float*)d_in[13];

  char* ws = (char*)d_ws;
  unsigned short* qb   = (unsigned short*)(ws + 0);         //  8.4 MB [4096,1024]
  unsigned short* keyb = (unsigned short*)(ws + 8388608);
  unsigned short* valb = (unsigned short*)(ws + 16777216);
  unsigned short* Wqb  = (unsigned short*)(ws + 25165824);  //  2.1 MB each
  unsigned short* Wkb  = (unsigned short*)(ws + 27262976);
  unsigned short* Wvb  = (unsigned short*)(ws + 29360128);
  unsigned short* Wob  = (unsigned short*)(ws + 31457280);
  unsigned short* rWb  = (unsigned short*)(ws + 33554432);  //  9.4 MB [2048,2304]
  unsigned short* Qbf  = (unsigned short*)(ws + 42991616);  //  Q/8, [4096,1024]
  unsigned short* KcT  = (unsigned short*)(ws + 51380224);  //  [b][1024][2304]
  unsigned short* VcT  = (unsigned short*)(ws + 60817408);
  unsigned short* Knew = (unsigned short*)(ws + 70254592);  //  [b][2048][1024]
  unsigned short* Vt   = (unsigned short*)(ws + 78643200);  //  [b][1024][2048]
  unsigned short* xpre = (unsigned short*)(ws + 87031808);  //  [4096,1024]
  float*          alphab = (float*)(ws + 95420416);         //  [32,2048]

  float* out_x    = (float*)d_out;
  float* out_attn = out_x + (size_t)NB * LQ * HID;

  auto cast = [&](const float* in, unsigned short* o, size_t n) {
    int n8 = (int)(n >> 3);
    int blocks = (n8 + 255) / 256; if (blocks > 2048) blocks = 2048;
    cast_kernel<<<blocks, 256, 0, stream>>>(in, o, n8);
  };
  cast(query, qb,   (size_t)NB * LQ * HID);
  cast(key,   keyb, (size_t)NB * LKK * HID);
  cast(value, valb, (size_t)NB * LKK * HID);
  cast(Wq, Wqb, (size_t)HID * HID);
  cast(Wk, Wkb, (size_t)HID * HID);
  cast(Wv, Wvb, (size_t)HID * HID);
  cast(Wo, Wob, (size_t)HID * HID);
  cast(rW, rWb, (size_t)LKK * LSK);

  samp_T<<<dim3(4, 16, 2), 256, 0, stream>>>(sampled, KcT, VcT);

  // Q = (query Wq^T + bq)/8, standard layout
  gemm_bt<0, 0><<<dim3(8, 32, 1), 256, 0, stream>>>(qb, Wqb, bq, (void*)Qbf,
      4096, 1024, 1024, 1024, 0, 0, 0, 0, 0.125f);
  // K/V projections -> transposed into KcT/VcT cols [256,2304)
  gemm_bt<0, 1><<<dim3(8, 16, 2), 256, 0, stream>>>(keyb, Wkb, bk, (void*)KcT,
      2048, 1024, 1024, LSK, LS, (size_t)LKK * HID, 0, (size_t)HID * LSK, 1.0f);
  gemm_bt<0, 1><<<dim3(8, 16, 2), 256, 0, stream>>>(valb, Wvb, bv, (void*)VcT,
      2048, 1024, 1024, LSK, LS, (size_t)LKK * HID, 0, (size_t)HID * LSK, 1.0f);
  // seq-axis linear: Knew = rW @ Kc + rb (std), Vnew -> transposed per-head Vt
  gemm_bt<1, 0><<<dim3(8, 16, 2), 256, 0, stream>>>(rWb, KcT, rb, (void*)Knew,
      2048, 1024, LSK, 1024, 0, 0, (size_t)HID * LSK, (size_t)LKK * HID, 1.0f);
  gemm_bt<1, 1><<<dim3(8, 16, 2), 256, 0, stream>>>(rWb, VcT, rb, (void*)Vt,
      2048, 1024, LSK, LKK, 0, 0, (size_t)HID * LSK, (size_t)LKK * HID, 1.0f);

  attn_stats<<<dim3(16, 32), 256, 0, stream>>>(Qbf, Knew, alphab);
  attn_pv<<<dim3(16, 32), 256, 0, stream>>>(Qbf, Knew, Vt, alphab, out_attn, xpre);

  // x = xpre @ Wo^T + bo  (fp32 to d_out)
  gemm_bt<0, 2><<<dim3(8, 32, 1), 256, 0, stream>>>(xpre, Wob, bo, (void*)out_x,
      4096, 1024, 1024, 1024, 0, 0, 0, 0, 1.0f);
}

// Round 2
// 347.236 us; speedup vs baseline: 1.2246x; 1.2246x over previous
//
#include <hip/hip_runtime.h>
#include <cstdint>
#include <cstddef>

// Problem constants
#define NB   2
#define LQ   2048
#define LKK  2048
#define LS   256
#define HID  1024
#define NH   16
#define LSK  2304   // LS + LK

#define DEV __device__ __forceinline__

typedef __bf16 bf16x8 __attribute__((ext_vector_type(8)));
typedef __bf16 bf16x4 __attribute__((ext_vector_type(4)));
typedef float  f32x4  __attribute__((ext_vector_type(4)));
typedef unsigned short us8 __attribute__((ext_vector_type(8)));

DEV unsigned short f2bf(float f) {
  unsigned int u = __builtin_bit_cast(unsigned int, f);
  u = (u + 0x7fffu + ((u >> 16) & 1u)) >> 16;  // RNE
  return (unsigned short)u;
}
DEV bf16x8 ld_frag(const void* p) {
  uint4 v = *(const uint4*)p;
  return __builtin_bit_cast(bf16x8, v);
}
DEV void gload_lds16(const unsigned short* g, unsigned short* l) {
  __builtin_amdgcn_global_load_lds((const __attribute__((address_space(1))) unsigned int*)g,
                                   (__attribute__((address_space(3))) unsigned int*)l,
                                   16, 0, 0);
}

// rule-18 fence: order per-wave ds_write -> ds_read without a block barrier
#define LGKM_FENCE() do { asm volatile("s_waitcnt lgkmcnt(0)" ::: "memory"); \
                          __builtin_amdgcn_sched_barrier(0); } while (0)

// ---------------- fused fp32 -> bf16 cast over 8 segments ----------------
struct CastParams { const float* src[8]; unsigned short* dst[8]; int end8[8]; int total8; };

__global__ __launch_bounds__(256)
void cast_all(CastParams p) {
  const int stride = gridDim.x * blockDim.x;
  for (int i = blockIdx.x * blockDim.x + threadIdx.x; i < p.total8; i += stride) {
    int s = 0;
    while (i >= p.end8[s]) ++s;
    int base = s ? p.end8[s - 1] : 0;
    size_t off = (size_t)(i - base) * 8;
    const float4* q = (const float4*)(p.src[s] + off);
    float4 a = q[0], b = q[1];
    us8 o;
    o[0] = f2bf(a.x); o[1] = f2bf(a.y); o[2] = f2bf(a.z); o[3] = f2bf(a.w);
    o[4] = f2bf(b.x); o[5] = f2bf(b.y); o[6] = f2bf(b.z); o[7] = f2bf(b.w);
    *(us8*)(p.dst[s] + off) = o;
  }
}

// ---------------- sampled^T into KcT/VcT cols [0,256) ----------------
__global__ __launch_bounds__(256)
void samp_T(const float* __restrict__ samp, unsigned short* __restrict__ KcT,
            unsigned short* __restrict__ VcT) {
  __shared__ unsigned short tl[64][65];
  const int b = blockIdx.z, st = blockIdx.x, nt = blockIdx.y;
  const int tid = threadIdx.x;
  const int nl = tid & 63, sq = tid >> 6;
#pragma unroll
  for (int j = 0; j < 16; ++j) {
    int sl = sq * 16 + j;
    tl[sl][nl] = f2bf(samp[(size_t)(b * LS + st * 64 + sl) * HID + nt * 64 + nl]);
  }
  __syncthreads();
#pragma unroll
  for (int wv = 0; wv < 2; ++wv) {
    int idx = wv * 256 + tid;
    int n_local = idx >> 3, sc = idx & 7;
    us8 v;
#pragma unroll
    for (int j = 0; j < 8; ++j) v[j] = tl[sc * 8 + j][n_local];
    size_t o = (size_t)(b * HID + nt * 64 + n_local) * LSK + st * 64 + sc * 8;
    *(us8*)(KcT + o) = v;
    *(us8*)(VcT + o) = v;
  }
}

// ---------------- multi-slice bf16 GEMM: C = A[M,K] * BT[N,K]^T (+bias)*oscale ----------------
// flags: (epi) | (bias_row<<4); epi: 0 bf16 std, 1 bf16 transposed, 2 f32 std.
struct GDesc {
  const unsigned short* A;
  const unsigned short* BT;
  const float* bias;
  void* out;
  int ldo, moff, K, flags;
  float oscale;
};
struct GParams { GDesc d[6]; };

__global__ __launch_bounds__(256, 2)
void gemm_multi(GParams p) {
  __shared__ unsigned short lA[128 * 64];
  __shared__ unsigned short lB[128 * 64];
  const GDesc g = p.d[blockIdx.z];
  const int tid = threadIdx.x, l = tid & 63, w = tid >> 6;
  const int wr = w >> 1, wc = w & 1;
  const int m0 = blockIdx.y * 128, n0 = blockIdx.x * 128;
  const int K = g.K;
  const unsigned short* A = g.A;
  const unsigned short* BT = g.BT;
  f32x4 acc[4][4] = {};
  const int nk = K >> 6;
  for (int kt = 0; kt < nk; ++kt) {
    const int k0 = kt << 6;
#pragma unroll
    for (int it = 0; it < 4; ++it) {
      int s = it * 256 + tid;
      int t = s >> 3, c = s & 7, g2 = c ^ (t & 7);
      gload_lds16(A + (size_t)(m0 + t) * K + (k0 + g2 * 8), lA + (size_t)s * 8);
      gload_lds16(BT + (size_t)(n0 + t) * K + (k0 + g2 * 8), lB + (size_t)s * 8);
    }
    __syncthreads();
#pragma unroll
    for (int ks = 0; ks < 2; ++ks) {
      bf16x8 af[4], bfr[4];
#pragma unroll
      for (int mi = 0; mi < 4; ++mi) {
        int row = wr * 64 + mi * 16 + (l & 15);
        int ch = (ks * 4 + (l >> 4)) ^ (row & 7);
        af[mi] = ld_frag((const char*)lA + row * 128 + ch * 16);
      }
#pragma unroll
      for (int ni = 0; ni < 4; ++ni) {
        int row = wc * 64 + ni * 16 + (l & 15);
        int ch = (ks * 4 + (l >> 4)) ^ (row & 7);
        bfr[ni] = ld_frag((const char*)lB + row * 128 + ch * 16);
      }
#pragma unroll
      for (int mi = 0; mi < 4; ++mi)
#pragma unroll
        for (int ni = 0; ni < 4; ++ni)
          acc[mi][ni] = __builtin_amdgcn_mfma_f32_16x16x32_bf16(af[mi], bfr[ni], acc[mi][ni], 0, 0, 0);
    }
    __syncthreads();
  }
  const int epi = g.flags & 15, brow = g.flags >> 4;
  const int r4 = (l >> 4) * 4;
#pragma unroll
  for (int mi = 0; mi < 4; ++mi) {
    const int mbase = m0 + wr * 64 + mi * 16 + r4;
#pragma unroll
    for (int ni = 0; ni < 4; ++ni) {
      const int n = n0 + wc * 64 + ni * 16 + (l & 15);
      f32x4 v = acc[mi][ni];
      if (brow) {
#pragma unroll
        for (int r = 0; r < 4; ++r) v[r] = (v[r] + g.bias[mbase + r]) * g.oscale;
      } else {
        const float bn = g.bias[n];
#pragma unroll
        for (int r = 0; r < 4; ++r) v[r] = (v[r] + bn) * g.oscale;
      }
      if (epi == 0) {
        unsigned short* o = (unsigned short*)g.out;
#pragma unroll
        for (int r = 0; r < 4; ++r) o[(size_t)(mbase + r) * g.ldo + n] = f2bf(v[r]);
      } else if (epi == 1) {
        unsigned short* o = (unsigned short*)g.out;
        ushort4 pk;
        pk.x = f2bf(v[0]); pk.y = f2bf(v[1]); pk.z = f2bf(v[2]); pk.w = f2bf(v[3]);
        *(ushort4*)(o + (size_t)n * g.ldo + g.moff + mbase) = pk;
      } else {
        float* o = (float*)g.out;
#pragma unroll
        for (int r = 0; r < 4; ++r) o[(size_t)(mbase + r) * g.ldo + n] = v[r];
      }
    }
  }
}

// ---------------- fused attention: stats (pass 1) + attn store + PV (pass 2) ----------------
// Qb pre-scaled by 1/8. Swapped QK^T: e = mfma(K,Q) -> lane holds rows k=(l>>4)*4+r, col q=l&15.
// grid (LQ/128, B*NH), 256 threads (4 waves x 32 q-rows).
__global__ __launch_bounds__(256, 2)
void attn_fused(const unsigned short* __restrict__ Qb, const unsigned short* __restrict__ Kn,
                const unsigned short* __restrict__ Vt, float* __restrict__ attn_out,
                unsigned short* __restrict__ xpre) {
  __shared__ unsigned short smem[24576];  // 48 KB
  const int tid = threadIdx.x, l = tid & 63, w = tid >> 6;
  const int qt = blockIdx.x, bh = blockIdx.y, b = bh >> 4, h = bh & 15;
  const unsigned short* Qg = Qb + (size_t)(b * LQ + qt * 128) * HID + h * 64;
  const unsigned short* Kg = Kn + (size_t)(b * LKK) * HID + h * 64;
  const unsigned short* Vg = Vt + ((size_t)b * HID + h * 64) * LKK;  // [d][t]
  unsigned short* const lK0 = smem;           // 8 KB (also lQ staging area with lK1)
  unsigned short* const lK1 = smem + 4096;
  unsigned short* const lV0 = smem + 8192;
  unsigned short* const lV1 = smem + 12288;
  unsigned short* const lPw = smem + 16384 + w * 2048;  // per-wave 32x64 bf16 P tile

  // ---- stage Q tile (128x64) through smem[0..8192), read fragments, release ----
#pragma unroll
  for (int it = 0; it < 4; ++it) {
    int s = it * 256 + tid, t = s >> 3, c = s & 7, g2 = c ^ (t & 7);
    gload_lds16(Qg + (size_t)t * HID + g2 * 8, smem + (size_t)s * 8);
  }
  __syncthreads();
  bf16x8 qf[2][2];
#pragma unroll
  for (int qi = 0; qi < 2; ++qi)
#pragma unroll
    for (int ds = 0; ds < 2; ++ds) {
      int row = w * 32 + qi * 16 + (l & 15);
      int ch = (ds * 4 + (l >> 4)) ^ (row & 7);
      qf[qi][ds] = ld_frag((const char*)smem + row * 128 + ch * 16);
    }
  __syncthreads();

  auto stageK = [&](int kt, unsigned short* dst) {
#pragma unroll
    for (int it = 0; it < 2; ++it) {
      int s = it * 256 + tid, t = s >> 3, c = s & 7, g2 = c ^ (t & 7);
      gload_lds16(Kg + (size_t)(kt * 64 + t) * HID + g2 * 8, dst + (size_t)s * 8);
    }
  };
  auto stageV = [&](int kt, unsigned short* dst) {
#pragma unroll
    for (int it = 0; it < 2; ++it) {
      int s = it * 256 + tid, t = s >> 3, c = s & 7, g2 = c ^ (t & 7);
      gload_lds16(Vg + (size_t)t * LKK + kt * 64 + g2 * 8, dst + (size_t)s * 8);
    }
  };

  // ---- phase 1: per-row max + logsumexp (K re-read, no stores) ----
  float mx[2] = { -1e30f, -1e30f }, sm[2] = { 0.0f, 0.0f };
  stageK(0, lK0);
  __syncthreads();
  for (int kt = 0; kt < 32; ++kt) {
    if (kt < 31) stageK(kt + 1, (kt & 1) ? lK0 : lK1);
    const unsigned short* cK = (kt & 1) ? lK1 : lK0;
    f32x4 e[4][2] = {};
#pragma unroll
    for (int ds = 0; ds < 2; ++ds) {
      bf16x8 kf[4];
#pragma unroll
      for (int ki = 0; ki < 4; ++ki) {
        int row = ki * 16 + (l & 15);
        int ch = (ds * 4 + (l >> 4)) ^ (row & 7);
        kf[ki] = ld_frag((const char*)cK + row * 128 + ch * 16);
      }
#pragma unroll
      for (int ki = 0; ki < 4; ++ki)
#pragma unroll
        for (int qi = 0; qi < 2; ++qi)
          e[ki][qi] = __builtin_amdgcn_mfma_f32_16x16x32_bf16(kf[ki], qf[qi][ds], e[ki][qi], 0, 0, 0);
    }
#pragma unroll
    for (int qi = 0; qi < 2; ++qi) {
      float tm = e[0][qi][0];
#pragma unroll
      for (int ki = 0; ki < 4; ++ki)
#pragma unroll
        for (int r = 0; r < 4; ++r) tm = fmaxf(tm, e[ki][qi][r]);
      float mo = mx[qi], mn = fmaxf(mo, tm);
      float s_ = sm[qi] * __expf(mo - mn);
#pragma unroll
      for (int ki = 0; ki < 4; ++ki)
#pragma unroll
        for (int r = 0; r < 4; ++r) s_ += __expf(e[ki][qi][r] - mn);
      mx[qi] = mn; sm[qi] = s_;
    }
    __syncthreads();
  }
  // butterfly across the 4 lane-groups sharing q = qi*16 + (l&15)
  float al[2];
#pragma unroll
  for (int qi = 0; qi < 2; ++qi) {
    float mm = mx[qi], ss = sm[qi];
#pragma unroll
    for (int mask = 16; mask <= 32; mask <<= 1) {
      float om = __shfl_xor(mm, mask, 64);
      float os = __shfl_xor(ss, mask, 64);
      float mn = fmaxf(mm, om);
      ss = ss * __expf(mm - mn) + os * __expf(om - mn);
      mm = mn;
    }
    al[qi] = mm + __logf(ss);  // alpha: exp(e - al) is normalized
  }

  // ---- phase 2: recompute E, store normalized attn (f32), PV ----
  stageK(0, lK0); stageV(0, lV0);
  __syncthreads();
  f32x4 x[2][4] = {};
  float* attn_base = attn_out + ((size_t)bh * LQ + qt * 128 + w * 32) * LKK;
  for (int kt = 0; kt < 32; ++kt) {
    if (kt < 31) {
      stageK(kt + 1, (kt & 1) ? lK0 : lK1);
      stageV(kt + 1, (kt & 1) ? lV0 : lV1);
    }
    const unsigned short* cK = (kt & 1) ? lK1 : lK0;
    const unsigned short* cV = (kt & 1) ? lV1 : lV0;
    f32x4 e[4][2] = {};
#pragma unroll
    for (int ds = 0; ds < 2; ++ds) {
      bf16x8 kf[4];
#pragma unroll
      for (int ki = 0; ki < 4; ++ki) {
        int row = ki * 16 + (l & 15);
        int ch = (ds * 4 + (l >> 4)) ^ (row & 7);
        kf[ki] = ld_frag((const char*)cK + row * 128 + ch * 16);
      }
#pragma unroll
      for (int ki = 0; ki < 4; ++ki)
#pragma unroll
        for (int qi = 0; qi < 2; ++qi)
          e[ki][qi] = __builtin_amdgcn_mfma_f32_16x16x32_bf16(kf[ki], qf[qi][ds], e[ki][qi], 0, 0, 0);
    }
    // P = exp(e - al): f32 float4 store straight to attn_out; bf16x4 into lPw for PV
#pragma unroll
    for (int qi = 0; qi < 2; ++qi) {
      const int q = qi * 16 + (l & 15);
      float* arow = attn_base + (size_t)q * LKK + kt * 64 + ((l >> 4) << 2);
#pragma unroll
      for (int ki = 0; ki < 4; ++ki) {
        float p0 = __expf(e[ki][qi][0] - al[qi]);
        float p1 = __expf(e[ki][qi][1] - al[qi]);
        float p2 = __expf(e[ki][qi][2] - al[qi]);
        float p3 = __expf(e[ki][qi][3] - al[qi]);
        float4 st; st.x = p0; st.y = p1; st.z = p2; st.w = p3;
        *(float4*)(arow + ki * 16) = st;   // k = ki*16 + (l>>4)*4 + r : consecutive over r
        bf16x4 pk;
        pk[0] = (__bf16)p0; pk[1] = (__bf16)p1; pk[2] = (__bf16)p2; pk[3] = (__bf16)p3;
        int chv = (ki * 2 + (l >> 5)) ^ (l & 7);           // chunk(k0>>3) ^ (q&7)
        *(bf16x4*)(lPw + q * 64 + chv * 8 + ((l >> 4) & 1) * 4) = pk;
      }
    }
    LGKM_FENCE();  // per-wave P tile: ds_write -> ds_read ordering, no block barrier needed
    // PV: x += P * V  (stores retire under these MFMAs before the end barrier)
#pragma unroll
    for (int ks = 0; ks < 2; ++ks) {
      bf16x8 pa[2], vb[4];
#pragma unroll
      for (int qi = 0; qi < 2; ++qi) {
        int row = qi * 16 + (l & 15);
        int ch = (ks * 4 + (l >> 4)) ^ (row & 7);
        pa[qi] = ld_frag((const char*)lPw + row * 128 + ch * 16);
      }
#pragma unroll
      for (int df = 0; df < 4; ++df) {
        int row = df * 16 + (l & 15);
        int ch = (ks * 4 + (l >> 4)) ^ (row & 7);
        vb[df] = ld_frag((const char*)cV + row * 128 + ch * 16);
      }
#pragma unroll
      for (int qi = 0; qi < 2; ++qi)
#pragma unroll
        for (int df = 0; df < 4; ++df)
          x[qi][df] = __builtin_amdgcn_mfma_f32_16x16x32_bf16(pa[qi], vb[df], x[qi][df], 0, 0, 0);
    }
    __syncthreads();
  }
#pragma unroll
  for (int qi = 0; qi < 2; ++qi)
#pragma unroll
    for (int df = 0; df < 4; ++df)
#pragma unroll
      for (int r = 0; r < 4; ++r)
        xpre[(size_t)(b * LQ + qt * 128 + w * 32 + qi * 16 + (l >> 4) * 4 + r) * HID
             + h * 64 + df * 16 + (l & 15)] = f2bf(x[qi][df][r]);
}

// ---------------- launcher ----------------
extern "C" void kernel_launch(void* const* d_in, const int* in_sizes, int n_in,
                              void* d_out, int out_size, void* d_ws, size_t ws_size,
                              hipStream_t stream) {
  (void)in_sizes; (void)n_in; (void)out_size; (void)ws_size;
  const float* query   = (const float*)d_in[0];
  const float* sampled = (const float*)d_in[1];
  const float* key     = (const float*)d_in[2];
  const float* value   = (const float*)d_in[3];
  const float* Wq = (const float*)d_in[4];  const float* bq = (const float*)d_in[5];
  const float* Wk = (const float*)d_in[6];  const float* bk = (const float*)d_in[7];
  const float* Wv = (const float*)d_in[8];  const float* bv = (const float*)d_in[9];
  const float* Wo = (const float*)d_in[10]; const float* bo = (const float*)d_in[11];
  const float* rW = (const float*)d_in[12]; const float* rb = (const float*)d_in[13];

  char* ws = (char*)d_ws;
  unsigned short* qb   = (unsigned short*)(ws + 0);
  unsigned short* keyb = (unsigned short*)(ws + 8388608);
  unsigned short* valb = (unsigned short*)(ws + 16777216);
  unsigned short* Wqb  = (unsigned short*)(ws + 25165824);
  unsigned short* Wkb  = (unsigned short*)(ws + 27262976);
  unsigned short* Wvb  = (unsigned short*)(ws + 29360128);
  unsigned short* Wob  = (unsigned short*)(ws + 31457280);
  unsigned short* rWb  = (unsigned short*)(ws + 33554432);
  unsigned short* Qbf  = (unsigned short*)(ws + 42991616);
  unsigned short* KcT  = (unsigned short*)(ws + 51380224);
  unsigned short* VcT  = (unsigned short*)(ws + 60817408);
  unsigned short* Knew = (unsigned short*)(ws + 70254592);
  unsigned short* Vt   = (unsigned short*)(ws + 78643200);
  unsigned short* xpre = (unsigned short*)(ws + 87031808);

  float* out_x    = (float*)d_out;
  float* out_attn = out_x + (size_t)NB * LQ * HID;

  // one cast launch for all fp32->bf16 segments
  CastParams cp;
  const float* srcs[8] = { query, key, value, Wq, Wk, Wv, Wo, rW };
  unsigned short* dsts[8] = { qb, keyb, valb, Wqb, Wkb, Wvb, Wob, rWb };
  const int sz8[8] = { 524288, 524288, 524288, 131072, 131072, 131072, 131072, 589824 };
  int acc = 0;
  for (int i = 0; i < 8; ++i) { cp.src[i] = srcs[i]; cp.dst[i] = dsts[i]; acc += sz8[i]; cp.end8[i] = acc; }
  cp.total8 = acc;
  cast_all<<<2048, 256, 0, stream>>>(cp);

  samp_T<<<dim3(4, 16, 2), 256, 0, stream>>>(sampled, KcT, VcT);

  // merged Q/K/V projections (z = 6): Q scaled 1/8 std; K/V transposed into KcT/VcT
  GParams pp{};
  for (int b = 0; b < 2; ++b) {
    pp.d[b]     = { qb   + (size_t)b * 2048 * 1024, Wqb, bq, (void*)(Qbf + (size_t)b * 2048 * 1024),
                    1024, 0, 1024, 0, 0.125f };
    pp.d[2 + b] = { keyb + (size_t)b * 2048 * 1024, Wkb, bk, (void*)(KcT + (size_t)b * HID * LSK),
                    LSK, LS, 1024, 1, 1.0f };
    pp.d[4 + b] = { valb + (size_t)b * 2048 * 1024, Wvb, bv, (void*)(VcT + (size_t)b * HID * LSK),
                    LSK, LS, 1024, 1, 1.0f };
  }
  gemm_multi<<<dim3(8, 16, 6), 256, 0, stream>>>(pp);

  // merged seq-axis linear (z = 4): Knew std; Vnew transposed per-head into Vt
  GParams sp{};
  for (int b = 0; b < 2; ++b) {
    sp.d[b]     = { rWb, KcT + (size_t)b * HID * LSK, rb, (void*)(Knew + (size_t)b * 2048 * 1024),
                    1024, 0, LSK, 0 | 16, 1.0f };
    sp.d[2 + b] = { rWb, VcT + (size_t)b * HID * LSK, rb, (void*)(Vt + (size_t)b * HID * LKK),
                    LKK, 0, LSK, 1 | 16, 1.0f };
  }
  gemm_multi<<<dim3(8, 16, 4), 256, 0, stream>>>(sp);

  attn_fused<<<dim3(16, 32), 256, 0, stream>>>(Qbf, Knew, Vt, out_attn, xpre);

  // x = xpre @ Wo^T + bo (fp32 out)
  GParams op{};
  op.d[0] = { xpre, Wob, bo, (void*)out_x, 1024, 0, 1024, 2, 1.0f };
  gemm_multi<<<dim3(8, 32, 1), 256, 0, stream>>>(op);
}